// Round 14
// baseline (321.930 us; speedup 1.0000x reference)
//
#include <hip/hip_runtime.h>

typedef _Float16 f16x8 __attribute__((ext_vector_type(8)));
typedef _Float16 f16x4 __attribute__((ext_vector_type(4)));
typedef __fp16 fp16v2 __attribute__((ext_vector_type(2)));
typedef _Float16 f16v2 __attribute__((ext_vector_type(2)));
typedef short short8 __attribute__((ext_vector_type(8)));
typedef float f32x16 __attribute__((ext_vector_type(16)));

#define DD 512
#define NG 512

typedef __attribute__((address_space(3))) void lds_void;
typedef __attribute__((address_space(1))) void glb_void;

static __device__ __forceinline__ void gload_lds16(const void* g, void* l) {
  __builtin_amdgcn_global_load_lds((const glb_void*)g, (lds_void*)l, 16, 0, 0);
}

// packed f32x2 -> f16x2 (RTZ), bit-cast to _Float16 vector
static __device__ __forceinline__ f16v2 pk16(float a, float b) {
  fp16v2 p = __builtin_amdgcn_cvt_pkrtz(a, b);
  return __builtin_bit_cast(f16v2, p);
}

// fast tanh: 1 - 2/(e^{2v}+1), native exp/rcp (~1e-6 abs err, saturates correctly)
static __device__ __forceinline__ float fast_tanh(float v) {
  float e = __expf(2.0f * v);
  return 1.0f - 2.0f * __builtin_amdgcn_rcpf(e + 1.0f);
}

// Whl layout (f16 RTE): [cq(4)][kt(32)][ct(4)][lane(64)=khalf*32+c31][8 f16]
// One col-quarter = 128 KB contiguous -> staged ONCE per block into LDS.
// B-fragment ds_read = ldsW + kt*4096 + ct*1024 + lane*16: 64 lanes read
// 1024 contiguous bytes -> zero bank conflicts (layout family verified R4/R9).
__global__ __launch_bounds__(256) void k_convert_w(const float* __restrict__ W,
                                                   unsigned char* __restrict__ Whl) {
  int t = blockIdx.x * 256 + threadIdx.x;   // 32768 = 512 W-rows x 64 kgroups(8)
  int r512 = t >> 6, kg = t & 63;
  int cq = r512 >> 7, rq = r512 & 127;
  int ct = rq >> 5, c31 = rq & 31;
  int kt = kg >> 1, khalf = kg & 1;
  const float* p = W + (size_t)r512 * DD + kg * 8;
  short8 h;
#pragma unroll
  for (int j = 0; j < 8; ++j) {
    _Float16 hh = (_Float16)p[j];              // RTE
    h[j] = (short)__builtin_bit_cast(unsigned short, hh);
  }
  unsigned char* dst = Whl + (size_t)cq * 131072 + (size_t)kt * 4096 +
                       ct * 1024 + (khalf * 32 + c31) * 16;
  *(short8*)dst = h;
}

// Fused GEMM(tanh-gate) + query-dot, persistent-W design.
// Block = 8 waves (512 thr) x 64 rows = 512 rows, 128 cols (blockIdx.x = cq).
// W-quarter (128 KB f16) staged into LDS ONCE; main loop has NO barriers and
// NO B staging.  A is wave-private: coalesced f32 loads -> pkrtz -> ds_write
// (2 KB buf; same-wave LDS in-order => no sync).  Body kt: read A(kt) frags
// [written last body] + B frags -> 8 MFMA; then write A(kt+1), gload A(kt+3).
// 144 KB LDS -> 1 block/CU, 2 waves/SIMD, free-running waves.
__global__ __launch_bounds__(512, 2) void k_gemm_score(
    const float* __restrict__ x, const unsigned char* __restrict__ Whl,
    const float* __restrict__ bias, const float* __restrict__ query,
    float* __restrict__ score_part, int N) {
  __shared__ unsigned char ldsW[131072];
  __shared__ unsigned char ldsA[8][2048];
  const int tid = threadIdx.x;
  const int wave = tid >> 6;
  const int lane = tid & 63;
  const int l31 = lane & 31;
  const int kh = lane >> 5;          // k-half within fragment
  const int cq = blockIdx.x;         // col quarter (fastest -> L3 x-sharing)
  const int brow0 = blockIdx.y * 512;

  // ---- stage W quarter: 128 KB, 512 thr x 16 B x 16 rounds ----
  {
    const unsigned char* wsrc = Whl + (size_t)cq * 131072 + (size_t)tid * 16;
#pragma unroll
    for (int i = 0; i < 16; ++i)
      gload_lds16(wsrc + i * 8192, &ldsW[tid * 16 + i * 8192]);
  }

  // ---- A pipeline setup (wave-private) ----
  // gload inst j covers rows wave*64 + j*16 + (lane>>2), 16B at koff (lane&3)*4
  const float* asrc = x + (size_t)(brow0 + wave * 64 + (lane >> 2)) * DD + (lane & 3) * 4;
  unsigned char* awr = &ldsA[wave][(lane >> 2) * 32 + (lane & 3) * 8];
  const unsigned char* ard0 = &ldsA[wave][l31 * 32 + kh * 16];          // rows 0..31
  const unsigned char* ard1 = &ldsA[wave][(32 + l31) * 32 + kh * 16];   // rows 32..63
  const unsigned char* wb = &ldsW[lane * 16];

  f32x16 acc[2][4];
#pragma unroll
  for (int f = 0; f < 2; ++f)
#pragma unroll
    for (int j = 0; j < 4; ++j)
#pragma unroll
      for (int r = 0; r < 16; ++r) acc[f][j][r] = 0.f;

  float4 aR[2][4];
#pragma unroll
  for (int j = 0; j < 4; ++j) aR[0][j] = *(const float4*)(asrc + j * 16 * DD);
#pragma unroll
  for (int j = 0; j < 4; ++j) aR[1][j] = *(const float4*)(asrc + j * 16 * DD + 16);

#define AWRITE(S)                                                      \
  do {                                                                 \
    _Pragma("unroll")                                                  \
    for (int j = 0; j < 4; ++j) {                                      \
      f16v2 p0_ = pk16(aR[S][j].x, aR[S][j].y);                        \
      f16v2 p1_ = pk16(aR[S][j].z, aR[S][j].w);                        \
      f16x4 v_ = {p0_[0], p0_[1], p1_[0], p1_[1]};                     \
      *(f16x4*)(awr + j * 512) = v_;                                   \
    }                                                                  \
  } while (0)

  // write A(0); refill set 0 with A(2); barrier once (W + everyone's A ready)
  asm volatile("s_waitcnt vmcnt(0)" ::: "memory");   // W gload_lds + A loads landed
  AWRITE(0);
#pragma unroll
  for (int j = 0; j < 4; ++j) aR[0][j] = *(const float4*)(asrc + j * 16 * DD + 32);
  __syncthreads();

  // ---- main loop: NO barriers, NO B staging ----
#pragma unroll 2
  for (int kt = 0; kt < 32; ++kt) {
    const int t1 = (kt + 1) & 1;       // reg set holding A(kt+1)
    // A fragments of kt (written in previous body / prologue)
    f16x8 a0 = *(const f16x8*)(ard0);
    f16x8 a1 = *(const f16x8*)(ard1);
    const unsigned char* bb = wb + kt * 4096;
#pragma unroll
    for (int j = 0; j < 4; ++j) {
      f16x8 bh = *(const f16x8*)(bb + j * 1024);
      acc[0][j] = __builtin_amdgcn_mfma_f32_32x32x16_f16(a0, bh, acc[0][j], 0, 0, 0);
      acc[1][j] = __builtin_amdgcn_mfma_f32_32x32x16_f16(a1, bh, acc[1][j], 0, 0, 0);
    }
    // stage A(kt+1) into LDS (after the reads above - program order keeps it safe),
    // then refill that reg set with A(kt+3)
    AWRITE(t1);
    const int km = (kt + 3) & 31;
#pragma unroll
    for (int j = 0; j < 4; ++j)
      aR[t1][j] = *(const float4*)(asrc + j * 16 * DD + km * 16);
  }

  // ---- epilogue: tanh + query-dot; reduce over 32 col-lanes; direct store ----
  float sp[2][16];
#pragma unroll
  for (int f = 0; f < 2; ++f)
#pragma unroll
    for (int r = 0; r < 16; ++r) sp[f][r] = 0.f;
#pragma unroll
  for (int j = 0; j < 4; ++j) {
    const int col = cq * 128 + j * 32 + l31;
    const float bb2 = bias[col];
    const float qq = query[col];
#pragma unroll
    for (int f = 0; f < 2; ++f)
#pragma unroll
      for (int r = 0; r < 16; ++r)
        sp[f][r] += fast_tanh(acc[f][j][r] + bb2) * qq;
  }
#pragma unroll
  for (int f = 0; f < 2; ++f)
#pragma unroll
    for (int r = 0; r < 16; ++r) {
      float v = sp[f][r];
      v += __shfl_xor(v, 1);
      v += __shfl_xor(v, 2);
      v += __shfl_xor(v, 4);
      v += __shfl_xor(v, 8);
      v += __shfl_xor(v, 16);
      if (l31 == 0)  // C row = (r&3) + 8*(r>>2) + 4*kh  (m74/m101 layout)
        score_part[(size_t)cq * N + brow0 + wave * 64 + f * 32 +
                   (r & 3) + 8 * (r >> 2) + 4 * kh] = v;
    }
}

// Per-graph: segmented softmax over sum of 4 partials + weighted x-sum -> out[g][512]
__global__ __launch_bounds__(256) void k_softmax_out(
    const float* __restrict__ x, const void* __restrict__ segp,
    const float* __restrict__ sp, float* __restrict__ out, int N) {
  const int g = blockIdx.x;
  const int tid = threadIdx.x;

  // dtype probe: int64 element N/2-1 is a graph id (<NG) iff buffer is int64.
  const long long probe = ((const long long*)segp)[N / 2 - 1];
  const bool is64 = ((unsigned long long)probe < (unsigned long long)NG);
  const long long* s64 = (const long long*)segp;
  const int* s32 = (const int*)segp;

  int s0, s1;
  {
    int lo = 0, hi = N;
    while (lo < hi) {
      int m = (lo + hi) >> 1;
      long long v = is64 ? s64[m] : (long long)s32[m];
      if (v < (long long)g) lo = m + 1; else hi = m;
    }
    s0 = lo;
    lo = s0; hi = N;
    while (lo < hi) {
      int m = (lo + hi) >> 1;
      long long v = is64 ? s64[m] : (long long)s32[m];
      if (v < (long long)(g + 1)) lo = m + 1; else hi = m;
    }
    s1 = lo;
  }

  __shared__ float red[4];
  __shared__ float wbuf[512];

#define SCORE(i) (sp[i] + sp[N + (i)] + sp[2 * N + (i)] + sp[3 * N + (i)])

  float lm = -INFINITY;
  for (int i = s0 + tid; i < s1; i += 256) lm = fmaxf(lm, SCORE(i));
#pragma unroll
  for (int m = 1; m < 64; m <<= 1) lm = fmaxf(lm, __shfl_xor(lm, m));
  if ((tid & 63) == 0) red[tid >> 6] = lm;
  __syncthreads();
  const float mx = fmaxf(fmaxf(red[0], red[1]), fmaxf(red[2], red[3]));
  __syncthreads();

  float ls = 0.f;
  for (int i = s0 + tid; i < s1; i += 256) ls += expf(SCORE(i) - mx);
#pragma unroll
  for (int m = 1; m < 64; m <<= 1) ls += __shfl_xor(ls, m);
  if ((tid & 63) == 0) red[tid >> 6] = ls;
  __syncthreads();
  const float sum = red[0] + red[1] + red[2] + red[3];
  const float inv = sum > 0.f ? 1.0f / sum : 0.f;

  float a0 = 0.f, a1 = 0.f;
  const int c = tid * 2;
  for (int base = s0; base < s1; base += 512) {
    const int cnt = min(512, s1 - base);
    __syncthreads();
    for (int i = tid; i < cnt; i += 256)
      wbuf[i] = expf(SCORE(base + i) - mx) * inv;
    __syncthreads();
#pragma unroll 4
    for (int j = 0; j < cnt; ++j) {
      const float w = wbuf[j];
      const float2 xv = *(const float2*)(x + (size_t)(base + j) * DD + c);
      a0 = fmaf(w, xv.x, a0);
      a1 = fmaf(w, xv.y, a1);
    }
  }
  float* op = out + (size_t)g * DD + c;
  op[0] = a0;
  op[1] = a1;
}

extern "C" void kernel_launch(void* const* d_in, const int* in_sizes, int n_in,
                              void* d_out, int out_size, void* d_ws, size_t ws_size,
                              hipStream_t stream) {
  const float* x = (const float*)d_in[0];
  const void* seg = d_in[1];
  const float* W = (const float*)d_in[2];
  const float* b = (const float*)d_in[3];
  const float* q = (const float*)d_in[4];
  float* out = (float*)d_out;
  const int N = in_sizes[0] / DD;  // 131072

  unsigned char* Whl = (unsigned char*)d_ws;                 // 512 KB packed W (f16)
  float* sp = (float*)(Whl + 524288);                        // 4 x N partial scores

  k_convert_w<<<128, 256, 0, stream>>>(W, Whl);
  dim3 grid(4, N / 512);                                     // x = cq fastest -> x L3 sharing
  k_gemm_score<<<grid, 512, 0, stream>>>(x, Whl, b, q, sp, N);
  k_softmax_out<<<NG, 256, 0, stream>>>(x, seg, sp, out, N);
}

// Round 15
// 217.299 us; speedup vs baseline: 1.4815x; 1.4815x over previous
//
#include <hip/hip_runtime.h>

typedef _Float16 f16x8 __attribute__((ext_vector_type(8)));
typedef _Float16 f16x4 __attribute__((ext_vector_type(4)));
typedef __fp16 fp16v2 __attribute__((ext_vector_type(2)));
typedef _Float16 f16v2 __attribute__((ext_vector_type(2)));
typedef short short8 __attribute__((ext_vector_type(8)));
typedef float f32x16 __attribute__((ext_vector_type(16)));

#define DD 512
#define NG 512

typedef __attribute__((address_space(3))) void lds_void;
typedef __attribute__((address_space(1))) void glb_void;

static __device__ __forceinline__ void gload_lds16(const void* g, void* l) {
  __builtin_amdgcn_global_load_lds((const glb_void*)g, (lds_void*)l, 16, 0, 0);
}

#define WAITV(n) asm volatile("s_waitcnt vmcnt(" #n ")" ::: "memory")
#define WAITL0 asm volatile("s_waitcnt lgkmcnt(0)" ::: "memory")
#define BAR __builtin_amdgcn_s_barrier()
#define MEMFENCE asm volatile("" ::: "memory")

static __device__ __forceinline__ f16v2 pk16(float a, float b) {
  fp16v2 p = __builtin_amdgcn_cvt_pkrtz(a, b);
  return __builtin_bit_cast(f16v2, p);
}

static __device__ __forceinline__ float fast_tanh(float v) {
  float e = __expf(2.0f * v);
  return 1.0f - 2.0f * __builtin_amdgcn_rcpf(e + 1.0f);
}

// Whl layout (f16 RTE): [ny(2)][kt(32)][ct(8)][lane(64)=khalf*32+c31][8 f16]
// kt = 16-k slice; a BK=64 K-step = 4 consecutive kt slices = 32 KB contiguous.
// B-fragment ds_read = base + ks*8192 + ct*1024 + lane*16 -> 1 KB contiguous
// per fragment, zero bank conflicts (verified R4/R9/R11).
__global__ __launch_bounds__(256) void k_convert_w(const float* __restrict__ W,
                                                   unsigned char* __restrict__ Whl) {
  int t = blockIdx.x * 256 + threadIdx.x;   // 32768 = 512 W-rows x 64 kgroups(8)
  int r512 = t >> 6, kg = t & 63;
  int ny = r512 >> 8, col = r512 & 255;
  int ct = col >> 5, c31 = col & 31;
  int kt = kg >> 1, khalf = kg & 1;
  const float* p = W + (size_t)r512 * DD + kg * 8;
  short8 h;
#pragma unroll
  for (int j = 0; j < 8; ++j) {
    _Float16 hh = (_Float16)p[j];              // RTE
    h[j] = (short)__builtin_bit_cast(unsigned short, hh);
  }
  unsigned char* dst = Whl + (size_t)ny * 262144 + (size_t)kt * 8192 +
                       ct * 1024 + (khalf * 32 + c31) * 16;
  *(short8*)dst = h;
}

// Fused GEMM(tanh-gate)+query-dot, 8-phase schedule (m201 template port).
// Block = 512 thr (8 waves: wr=wave>>2, wc=wave&3) = 256 rows x 256 cols
// (ny = blockIdx.x col-half).  BK=64 -> 8 K-steps x 4 phases.
// Wave tile 128x64: acc[4][2] f32x16 (128 AGPR).
// A: x f32 -> coalesced loads (4-line/instr) -> pkrtz -> ds_write b64 into
//    XOR'd planes [ks][kh][row^((ks<<1)|kh)][16B] - conflict-free both sides.
// B: global_load_lds linear (layout above).  Double-buffered A(32K)+B(32K).
// vmcnt(8) at ph0 (B(S) landed), vmcnt(4) at ph3 (A-regs landed); never 0.
__global__ __launch_bounds__(512, 2) void k_gemm_score(
    const float* __restrict__ x, const unsigned char* __restrict__ Whl,
    const float* __restrict__ bias, const float* __restrict__ query,
    float* __restrict__ score_part, int N) {
  __shared__ unsigned char ldsA[2][32768];
  __shared__ unsigned char ldsB[2][32768];
  __shared__ float comb[4][256];

  const int tid = threadIdx.x;
  const int wave = tid >> 6;
  const int lane = tid & 63;
  const int l31 = lane & 31;
  const int kh = lane >> 5;
  const int wr = wave >> 2;          // wave-row: rows wr*128..+127
  const int wc = wave & 3;           // wave-col: ct tiles wc*2, wc*2+1
  const int ny = blockIdx.x;
  const int brow0 = blockIdx.y * 256;

  const unsigned char* wsrc = Whl + (size_t)ny * 262144 + (size_t)tid * 16;
  // A global gather: instr j covers rows j*32 + (tid>>4) (block-rel), 16B f32
  // chunk kc=tid&15 of the 256B K-step window -> per wave-instr 4 rows x 256B
  // contiguous segments (4 cache lines).
  const float* asrc = x + (size_t)(brow0 + (tid >> 4)) * DD + (tid & 15) * 4;

  // A ds_write: chunk (ksA, hA, row) at plane-XOR'd slot row^cxor
  const int kc = tid & 15;
  const int ksA = kc >> 2, hA = (kc >> 1) & 1;
  const int cxor = (ksA << 1) | hA;
  const int awbase = ksA * 8192 + hA * 4096 + ((tid >> 4) ^ cxor) * 16 + (kc & 1) * 8;

  f32x16 acc[4][2];
#pragma unroll
  for (int rt = 0; rt < 4; ++rt)
#pragma unroll
    for (int ct = 0; ct < 2; ++ct)
#pragma unroll
      for (int r = 0; r < 16; ++r) acc[rt][ct][r] = 0.f;

  float4 aR[8];

#define BISSUE(SN, PB)                                                      \
  do {                                                                      \
    const unsigned char* sb_ = wsrc + (size_t)((SN) & 7) * 32768;           \
    _Pragma("unroll")                                                       \
    for (int i = 0; i < 4; ++i)                                             \
      gload_lds16(sb_ + i * 8192, &ldsB[PB][tid * 16 + i * 8192]);          \
  } while (0)

#define AISSUE(SN)                                                          \
  do {                                                                      \
    const int sm_ = (SN) & 7;                                               \
    _Pragma("unroll")                                                       \
    for (int j = 0; j < 8; ++j)                                             \
      aR[j] = *(const float4*)(asrc + (size_t)j * 32 * DD + sm_ * 64);      \
  } while (0)

#define AWRITE(PA)                                                          \
  do {                                                                      \
    _Pragma("unroll")                                                       \
    for (int j = 0; j < 8; ++j) {                                           \
      f16v2 lo_ = pk16(aR[j].x, aR[j].y);                                   \
      f16v2 hi_ = pk16(aR[j].z, aR[j].w);                                   \
      f16x4 v_ = {lo_[0], lo_[1], hi_[0], hi_[1]};                          \
      *(f16x4*)(&ldsA[PA][awbase + j * 512]) = v_;                          \
    }                                                                       \
  } while (0)

  // prologue: B(0)->ldsB[0]; A(0) regs; drain; A(0)->ldsA[0]; A(1) regs.
  BISSUE(0, 0);
  MEMFENCE;
  AISSUE(0);
  MEMFENCE;
  WAITV(0);
  AWRITE(0);
  AISSUE(1);
  MEMFENCE;
  WAITL0;
  BAR;

  // phase: frag reads -> [ph0: B-issue | ph3: A drain/write/issue] -> barrier
  //        -> 8 MFMA (setprio) -> [ph3: lgkm0] -> barrier
#define PHASE(S, KS)                                                        \
  do {                                                                      \
    const int p_ = (S) & 1;                                                 \
    if ((KS) == 0) WAITV(8); /* B(S) landed (8 A-loads newer) */            \
    const unsigned char* ab_ = &ldsA[p_][(KS) * 8192 + kh * 4096 +          \
        (wr * 128 + (l31 ^ (((KS) << 1) | kh))) * 16];                      \
    const unsigned char* bb_ = &ldsB[p_][(KS) * 8192 + wc * 2048 + lane * 16]; \
    f16x8 a0_ = *(const f16x8*)(ab_);                                       \
    f16x8 a1_ = *(const f16x8*)(ab_ + 512);                                 \
    f16x8 a2_ = *(const f16x8*)(ab_ + 1024);                                \
    f16x8 a3_ = *(const f16x8*)(ab_ + 1536);                                \
    f16x8 b0_ = *(const f16x8*)(bb_);                                       \
    f16x8 b1_ = *(const f16x8*)(bb_ + 1024);                                \
    if ((KS) == 0) { BISSUE((S) + 1, p_ ^ 1); }                             \
    if ((KS) == 3) {                                                        \
      WAITV(4); /* A(S+1) regs landed (4 B newer) */                        \
      AWRITE(p_ ^ 1);                                                       \
      AISSUE((S) + 2);                                                      \
    }                                                                       \
    MEMFENCE;                                                               \
    BAR;                                                                    \
    __builtin_amdgcn_s_setprio(1);                                          \
    acc[0][0] = __builtin_amdgcn_mfma_f32_32x32x16_f16(a0_, b0_, acc[0][0], 0, 0, 0); \
    acc[0][1] = __builtin_amdgcn_mfma_f32_32x32x16_f16(a0_, b1_, acc[0][1], 0, 0, 0); \
    acc[1][0] = __builtin_amdgcn_mfma_f32_32x32x16_f16(a1_, b0_, acc[1][0], 0, 0, 0); \
    acc[1][1] = __builtin_amdgcn_mfma_f32_32x32x16_f16(a1_, b1_, acc[1][1], 0, 0, 0); \
    acc[2][0] = __builtin_amdgcn_mfma_f32_32x32x16_f16(a2_, b0_, acc[2][0], 0, 0, 0); \
    acc[2][1] = __builtin_amdgcn_mfma_f32_32x32x16_f16(a2_, b1_, acc[2][1], 0, 0, 0); \
    acc[3][0] = __builtin_amdgcn_mfma_f32_32x32x16_f16(a3_, b0_, acc[3][0], 0, 0, 0); \
    acc[3][1] = __builtin_amdgcn_mfma_f32_32x32x16_f16(a3_, b1_, acc[3][1], 0, 0, 0); \
    __builtin_amdgcn_s_setprio(0);                                          \
    if ((KS) == 3) WAITL0; /* A ds_writes drained before next-step reads */ \
    MEMFENCE;                                                               \
    BAR;                                                                    \
  } while (0)

#define STEP(S) do { PHASE(S, 0); PHASE(S, 1); PHASE(S, 2); PHASE(S, 3); } while (0)

  STEP(0); STEP(1); STEP(2); STEP(3);
  STEP(4); STEP(5); STEP(6); STEP(7);

  // epilogue: tanh + query-dot over this wave's 64 cols; 32-lane reduce;
  // combine the 4 wave-cols via comb.
  float sp[4][16];
#pragma unroll
  for (int rt = 0; rt < 4; ++rt)
#pragma unroll
    for (int r = 0; r < 16; ++r) sp[rt][r] = 0.f;
#pragma unroll
  for (int ct = 0; ct < 2; ++ct) {
    const int col = ny * 256 + (wc * 2 + ct) * 32 + l31;
    const float bb2 = bias[col];
    const float qq = query[col];
#pragma unroll
    for (int rt = 0; rt < 4; ++rt)
#pragma unroll
      for (int r = 0; r < 16; ++r)
        sp[rt][r] += fast_tanh(acc[rt][ct][r] + bb2) * qq;
  }
#pragma unroll
  for (int rt = 0; rt < 4; ++rt)
#pragma unroll
    for (int r = 0; r < 16; ++r) {
      float v = sp[rt][r];
      v += __shfl_xor(v, 1);
      v += __shfl_xor(v, 2);
      v += __shfl_xor(v, 4);
      v += __shfl_xor(v, 8);
      v += __shfl_xor(v, 16);
      if (l31 == 0)  // C row = (r&3) + 8*(r>>2) + 4*kh  (m74/m101 layout)
        comb[wc][wr * 128 + rt * 32 + (r & 3) + 8 * (r >> 2) + 4 * kh] = v;
    }
  __syncthreads();
  if (tid < 256)
    score_part[(size_t)ny * N + brow0 + tid] =
        comb[0][tid] + comb[1][tid] + comb[2][tid] + comb[3][tid];
}

// Per-graph: segmented softmax over (sp0+sp1) + weighted sum of x rows -> out[g][512]
__global__ __launch_bounds__(256) void k_softmax_out(
    const float* __restrict__ x, const void* __restrict__ segp,
    const float* __restrict__ sp0, const float* __restrict__ sp1,
    float* __restrict__ out, int N) {
  const int g = blockIdx.x;
  const int tid = threadIdx.x;

  // dtype probe: int64 element N/2-1 is a graph id (<NG) iff buffer is int64.
  const long long probe = ((const long long*)segp)[N / 2 - 1];
  const bool is64 = ((unsigned long long)probe < (unsigned long long)NG);
  const long long* s64 = (const long long*)segp;
  const int* s32 = (const int*)segp;

  int s0, s1;
  {
    int lo = 0, hi = N;
    while (lo < hi) {
      int m = (lo + hi) >> 1;
      long long v = is64 ? s64[m] : (long long)s32[m];
      if (v < (long long)g) lo = m + 1; else hi = m;
    }
    s0 = lo;
    lo = s0; hi = N;
    while (lo < hi) {
      int m = (lo + hi) >> 1;
      long long v = is64 ? s64[m] : (long long)s32[m];
      if (v < (long long)(g + 1)) lo = m + 1; else hi = m;
    }
    s1 = lo;
  }

  __shared__ float red[4];
  __shared__ float wbuf[512];

  float lm = -INFINITY;
  for (int i = s0 + tid; i < s1; i += 256) lm = fmaxf(lm, sp0[i] + sp1[i]);
#pragma unroll
  for (int m = 1; m < 64; m <<= 1) lm = fmaxf(lm, __shfl_xor(lm, m));
  if ((tid & 63) == 0) red[tid >> 6] = lm;
  __syncthreads();
  const float mx = fmaxf(fmaxf(red[0], red[1]), fmaxf(red[2], red[3]));
  __syncthreads();

  float ls = 0.f;
  for (int i = s0 + tid; i < s1; i += 256) ls += expf(sp0[i] + sp1[i] - mx);
#pragma unroll
  for (int m = 1; m < 64; m <<= 1) ls += __shfl_xor(ls, m);
  if ((tid & 63) == 0) red[tid >> 6] = ls;
  __syncthreads();
  const float sum = red[0] + red[1] + red[2] + red[3];
  const float inv = sum > 0.f ? 1.0f / sum : 0.f;

  float a0 = 0.f, a1 = 0.f;
  const int c = tid * 2;
  for (int base = s0; base < s1; base += 512) {
    const int cnt = min(512, s1 - base);
    __syncthreads();
    for (int i = tid; i < cnt; i += 256)
      wbuf[i] = expf(sp0[base + i] + sp1[base + i] - mx) * inv;
    __syncthreads();
#pragma unroll 4
    for (int j = 0; j < cnt; ++j) {
      const float w = wbuf[j];
      const float2 xv = *(const float2*)(x + (size_t)(base + j) * DD + c);
      a0 = fmaf(w, xv.x, a0);
      a1 = fmaf(w, xv.y, a1);
    }
  }
  float* op = out + (size_t)g * DD + c;
  op[0] = a0;
  op[1] = a1;
}

extern "C" void kernel_launch(void* const* d_in, const int* in_sizes, int n_in,
                              void* d_out, int out_size, void* d_ws, size_t ws_size,
                              hipStream_t stream) {
  const float* x = (const float*)d_in[0];
  const void* seg = d_in[1];
  const float* W = (const float*)d_in[2];
  const float* b = (const float*)d_in[3];
  const float* q = (const float*)d_in[4];
  float* out = (float*)d_out;
  const int N = in_sizes[0] / DD;  // 131072

  unsigned char* Whl = (unsigned char*)d_ws;                 // 512 KB packed W (f16)
  float* sp0 = (float*)(Whl + 524288);                       // N partial scores (ny=0)
  float* sp1 = sp0 + N;                                      // N partial scores (ny=1)

  k_convert_w<<<128, 256, 0, stream>>>(W, Whl);
  dim3 grid(2, N / 256);                                     // ny fastest -> x-row L3 sharing
  k_gemm_score<<<grid, 512, 0, stream>>>(x, Whl, b, q, sp0, N);
  k_softmax_out<<<NG, 256, 0, stream>>>(x, seg, sp0, sp1, out, N);
}